// Round 1
// baseline (2381.872 us; speedup 1.0000x reference)
//
#include <hip/hip_runtime.h>
#include <math.h>

// WLN regressor, restructured:
//  - gather commutes with row-wise matmul: gather(X)@W == gather(X@W)
//  - kernel (W_na/W_sa path) only live at last depth; U1 update dead after depth 1
//  - bond-side projections (6->300) computed on the fly from LDS weights
// Workspace: 3 buffers of 32768x300 f32 = 118 MB.

static constexpr int Hh   = 300;
static constexpr int Bn   = 16;
static constexpr int Nn   = 2048;
static constexpr int Mm   = 4096;
static constexpr int Rn   = Bn * Nn;      // 32768 atom rows
static constexpr int NBn  = 10;

// ---------------------------------------------------------------------------
// GEMM: C[r, n] = act( sum_k Asel[r,k] * W[k,n] (+ bias[n]) ), W is K x 300.
// CONCAT: k<KA reads A (stride lda), else A2 (stride lda2). R % 128 == 0.
// BM=128, BN=64, BK=32, 256 threads, 8x4 accumulators per thread.
// ---------------------------------------------------------------------------
template<bool RELU, bool BIAS, bool CONCAT>
__global__ __launch_bounds__(256)
void gemm_k(const float* __restrict__ A, int lda,
            const float* __restrict__ A2, int lda2, int KA,
            const float* __restrict__ W,
            const float* __restrict__ bias,
            float* __restrict__ C,
            int K)
{
    constexpr int BM = 128, BN = 64, BK = 32;
    // +1 pad on inner dim: staging writes and the 8 scalar a-reads are conflict-free
    __shared__ __attribute__((aligned(16))) float As[BM][BK + 1];
    __shared__ __attribute__((aligned(16))) float Bs[BK][BN];

    const int t  = threadIdx.x;
    const int tx = t & 15;         // 16 col-threads * 4 cols = 64
    const int ty = t >> 4;         // 16 row-threads * 8 rows = 128
    const int rowBase = blockIdx.y * BM;
    const int colBase = blockIdx.x * BN;

    float acc[8][4];
#pragma unroll
    for (int i = 0; i < 8; i++)
#pragma unroll
        for (int j = 0; j < 4; j++) acc[i][j] = 0.f;

    for (int k0 = 0; k0 < K; k0 += BK) {
        // stage A tile: 128x32, 16 elems/thread, coalesced along k
#pragma unroll
        for (int e = 0; e < 16; e++) {
            int idx = t + e * 256;
            int m   = idx >> 5;
            int kk  = idx & 31;
            int k   = k0 + kk;
            float v = 0.f;
            if (k < K) {
                int r = rowBase + m;
                if (!CONCAT || k < KA) v = A[(size_t)r * lda + k];
                else                   v = A2[(size_t)r * lda2 + (k - KA)];
            }
            As[m][kk] = v;
        }
        // stage B tile: 32x64, 8 elems/thread, coalesced along n
#pragma unroll
        for (int e = 0; e < 8; e++) {
            int idx = t + e * 256;
            int kk  = idx >> 6;
            int n   = idx & 63;
            int k   = k0 + kk;
            int col = colBase + n;
            Bs[kk][n] = (k < K && col < Hh) ? W[(size_t)k * Hh + col] : 0.f;
        }
        __syncthreads();
#pragma unroll
        for (int kk = 0; kk < BK; kk++) {
            float4 b4 = *reinterpret_cast<const float4*>(&Bs[kk][tx * 4]);
            float a[8];
#pragma unroll
            for (int i = 0; i < 8; i++) a[i] = As[ty * 8 + i][kk];
#pragma unroll
            for (int i = 0; i < 8; i++) {
                acc[i][0] += a[i] * b4.x;
                acc[i][1] += a[i] * b4.y;
                acc[i][2] += a[i] * b4.z;
                acc[i][3] += a[i] * b4.w;
            }
        }
        __syncthreads();
    }
    // epilogue
#pragma unroll
    for (int i = 0; i < 8; i++) {
        int r = rowBase + ty * 8 + i;
#pragma unroll
        for (int j = 0; j < 4; j++) {
            int col = colBase + tx * 4 + j;
            if (col < Hh) {
                float v = acc[i][j];
                if (BIAS) v += bias[col];
                if (RELU) v = v > 0.f ? v : 0.f;
                C[(size_t)r * Hh + col] = v;
            }
        }
    }
}

// ---------------------------------------------------------------------------
// Gather over neighbors. One wave per node, 4 nodes per 256-thread block.
// LABEL (!FINAL): label[node,h] = sum_{k<nn} relu(Au2[ia,h] + (fb @ Wu2b)[h] + b_u2[h])
// FINAL:          f_nei[h] = sum_{k<nn} Ana[ia,h] * (fb @ Wnb)[h]
//                 dot      = sum_h f_nei[h]*Asa[node,h]*Wout[h] * nmask[node]
//                 atomicAdd(out[b], wave_reduce(dot))
// ---------------------------------------------------------------------------
template<bool FINAL>
__global__ __launch_bounds__(256)
void gather_k(const float* __restrict__ Arow,   // A_u2 or A_na  [R,300]
              const float* __restrict__ Asa,    // FINAL only    [R,300]
              const float* __restrict__ bond,   // [B*M, 6]
              const float* __restrict__ Wb,     // 6 x 300 (W_u2b or W_nb)
              const float* __restrict__ bias,   // b_u2 (LABEL only)
              const int*   __restrict__ ag,
              const int*   __restrict__ bg,
              const int*   __restrict__ nnb,
              const float* __restrict__ nmask,  // FINAL only
              const float* __restrict__ Wout,   // FINAL only
              float* __restrict__ outp)         // label [R,300] or out[B]
{
    __shared__ float sWb[6 * Hh];
    __shared__ float sV[Hh];                    // bias (LABEL) or Wout (FINAL)
    for (int i = threadIdx.x; i < 6 * Hh; i += 256) sWb[i] = Wb[i];
    if (FINAL) { for (int i = threadIdx.x; i < Hh; i += 256) sV[i] = Wout[i]; }
    else       { for (int i = threadIdx.x; i < Hh; i += 256) sV[i] = bias[i]; }
    __syncthreads();

    const int wave = threadIdx.x >> 6;
    const int lane = threadIdx.x & 63;
    const int node = blockIdx.x * 4 + wave;
    const int b    = node >> 11;               // N = 2048
    const int nn   = nnb[node];
    const int base = node * NBn;

    float acc[5] = {0.f, 0.f, 0.f, 0.f, 0.f};

    for (int k = 0; k < nn; k++) {             // nn wave-uniform: no divergence
        int ia = ag[base + k];
        int ib = bg[base + k];
        const float* pa = Arow + ((size_t)(b << 11) + ia) * Hh;
        const float* pf = bond + ((size_t)(b << 12) + ib) * 6;
        float f0 = pf[0], f1 = pf[1], f2 = pf[2], f3 = pf[3], f4 = pf[4], f5 = pf[5];
#pragma unroll
        for (int j = 0; j < 5; j++) {
            int h = lane + j * 64;
            if (j < 4 || h < Hh) {
                float w = f0 * sWb[h]            + f1 * sWb[Hh + h]
                        + f2 * sWb[2 * Hh + h]   + f3 * sWb[3 * Hh + h]
                        + f4 * sWb[4 * Hh + h]   + f5 * sWb[5 * Hh + h];
                float av = pa[h];
                if (FINAL) {
                    acc[j] += av * w;
                } else {
                    float v = av + w + sV[h];
                    acc[j] += v > 0.f ? v : 0.f;
                }
            }
        }
    }

    if (FINAL) {
        const float* psa = Asa + (size_t)node * Hh;
        float dot = 0.f;
#pragma unroll
        for (int j = 0; j < 5; j++) {
            int h = lane + j * 64;
            if (j < 4 || h < Hh) dot += acc[j] * psa[h] * sV[h];
        }
        dot *= nmask[node];
#pragma unroll
        for (int off = 32; off > 0; off >>= 1) dot += __shfl_down(dot, off, 64);
        if (lane == 0) atomicAdd(&outp[b], dot);
    } else {
        float* pl = outp + (size_t)node * Hh;
#pragma unroll
        for (int j = 0; j < 5; j++) {
            int h = lane + j * 64;
            if (j < 4 || h < Hh) pl[h] = acc[j];
        }
    }
}

__global__ void init_out_k(float* __restrict__ out, const float* __restrict__ b_out)
{
    if (threadIdx.x < Bn) out[threadIdx.x] = b_out[0];
}

// ---------------------------------------------------------------------------
extern "C" void kernel_launch(void* const* d_in, const int* in_sizes, int n_in,
                              void* d_out, int out_size, void* d_ws, size_t ws_size,
                              hipStream_t stream)
{
    const float* input_atom = (const float*)d_in[0];
    const float* input_bond = (const float*)d_in[1];
    const float* node_mask  = (const float*)d_in[2];
    const int*   atom_graph = (const int*)d_in[3];
    const int*   bond_graph = (const int*)d_in[4];
    const int*   num_nbs    = (const int*)d_in[5];
    const float* W_af       = (const float*)d_in[6];
    const float* W_na       = (const float*)d_in[7];
    const float* W_nb       = (const float*)d_in[8];
    const float* W_sa       = (const float*)d_in[9];
    const float* W_u2       = (const float*)d_in[10];
    const float* b_u2       = (const float*)d_in[11];
    const float* W_u1       = (const float*)d_in[12];
    const float* b_u1       = (const float*)d_in[13];
    const float* W_out      = (const float*)d_in[14];
    const float* b_out      = (const float*)d_in[15];
    float* out = (float*)d_out;

    const size_t S = (size_t)Rn * Hh;          // 9,830,400 floats per buffer
    float* buf0 = (float*)d_ws;                // needs 3*S*4 = 118 MB of ws
    float* buf1 = buf0 + S;
    float* buf2 = buf1 + S;                    // label / A_sa

    const float* W_u2b = W_u2 + (size_t)Hh * Hh;   // rows 300..305 of W_u2

    dim3 gemmGrid(5, Rn / 128);                // 300/64 -> 5 col tiles
    const int gatherBlocks = Rn / 4;

    init_out_k<<<dim3(1), dim3(64), 0, stream>>>(out, b_out);

    // atom_feat0 = relu(input_atom @ W_af)            -> buf0
    gemm_k<true, false, false><<<gemmGrid, 256, 0, stream>>>(
        input_atom, 82, nullptr, 0, 0, W_af, nullptr, buf0, 82);

    float* cur = buf0;
    float* oth = buf1;
    for (int d = 0; d < 2; d++) {
        // A_u2 = atom_feat @ W_u2[0:300]              -> oth
        gemm_k<false, false, false><<<gemmGrid, 256, 0, stream>>>(
            cur, Hh, nullptr, 0, 0, W_u2, nullptr, oth, Hh);
        // nei_label                                   -> buf2
        gather_k<false><<<gatherBlocks, 256, 0, stream>>>(
            oth, nullptr, input_bond, W_u2b, b_u2,
            atom_graph, bond_graph, num_nbs, nullptr, nullptr, buf2);
        // atom_feat' = relu(cat(atom_feat, nei_label) @ W_u1 + b_u1)  -> oth
        gemm_k<true, true, true><<<gemmGrid, 256, 0, stream>>>(
            cur, Hh, buf2, Hh, Hh, W_u1, b_u1, oth, 2 * Hh);
        float* tmp = cur; cur = oth; oth = tmp;
    }

    // depth 2: only the kernel output is live
    gemm_k<false, false, false><<<gemmGrid, 256, 0, stream>>>(
        cur, Hh, nullptr, 0, 0, W_na, nullptr, oth, Hh);    // A_na -> oth
    gemm_k<false, false, false><<<gemmGrid, 256, 0, stream>>>(
        cur, Hh, nullptr, 0, 0, W_sa, nullptr, buf2, Hh);   // A_sa -> buf2
    gather_k<true><<<gatherBlocks, 256, 0, stream>>>(
        oth, buf2, input_bond, W_nb, nullptr,
        atom_graph, bond_graph, num_nbs, node_mask, W_out, out);
}

// Round 2
// 552.569 us; speedup vs baseline: 4.3105x; 4.3105x over previous
//
#include <hip/hip_runtime.h>
#include <math.h>

// WLN regressor, bf16-MFMA version.
//  - gather commutes with row-wise matmul: gather(X)@W == gather(X@W)
//  - kernel (W_na/W_sa path) only live at last depth; U1 update dead after depth 1
//  - all GEMMs on matrix cores (16x16x32 bf16), activations bf16 [R][320] (N padded)
//  - weights converted+transposed+padded to bf16 on device each call
//  - bond-side projections (6->300) computed on the fly in fp32 from LDS weights

typedef unsigned short ushort_t;
typedef __attribute__((ext_vector_type(8))) short bf16x8;
typedef __attribute__((ext_vector_type(8))) unsigned short ushort8;
typedef __attribute__((ext_vector_type(4))) float f32x4;

static constexpr int Hh  = 300;
static constexpr int Hp  = 320;      // padded hidden (col dim & activation stride)
static constexpr int Bn  = 16;
static constexpr int Nn  = 2048;
static constexpr int Rn  = Bn * Nn;  // 32768 rows
static constexpr int NBn = 10;

__device__ __forceinline__ ushort_t f2bf(float x) {
    union { float f; unsigned u; } c; c.f = x;
    unsigned r = c.u + 0x7FFFu + ((c.u >> 16) & 1u);   // RNE
    return (ushort_t)(r >> 16);
}
__device__ __forceinline__ float bf2f(ushort_t h) {
    union { float f; unsigned u; } c; c.u = ((unsigned)h) << 16;
    return c.f;
}

// ---------------------------------------------------------------------------
// MFMA GEMM: C[r,n] = act( sum_k Asel[r,k]*Wt[n,k] (+bias[n]) ), C bf16 [R][320]
// A sources bf16 row-major (lda stride); Wt bf16 [320][KP] (pre-transposed,
// zero-padded). BM=256, BN=64, BK=32; 256 threads = 4 waves, each wave 64x64.
// LDS rows padded to 40 bf16 (80B) -> worst 2-way bank conflict (free, m136).
// ---------------------------------------------------------------------------
template<bool RELU, bool BIAS, bool CONCAT>
__global__ __launch_bounds__(256)
void mfma_gemm_k(const ushort_t* __restrict__ A, const ushort_t* __restrict__ A2,
                 int lda, int KP,
                 const ushort_t* __restrict__ Wt,
                 const float* __restrict__ bias,
                 ushort_t* __restrict__ C)
{
    __shared__ __attribute__((aligned(16))) ushort_t As[256 * 40];
    __shared__ __attribute__((aligned(16))) ushort_t Bs[64 * 40];

    const int t   = threadIdx.x;
    const int wv  = t >> 6;
    const int ln  = t & 63;
    const int lrow = ln & 15;          // fragment row/col within 16
    const int lgrp = ln >> 4;          // k-group 0..3
    const int rowBase = blockIdx.y * 256;
    const int nBase   = blockIdx.x * 64;

    f32x4 acc[4][4];
#pragma unroll
    for (int i = 0; i < 4; i++)
#pragma unroll
        for (int j = 0; j < 4; j++) acc[i][j] = (f32x4){0.f, 0.f, 0.f, 0.f};

    const int half = KP >> 1;          // concat split point (=320)

    for (int k0 = 0; k0 < KP; k0 += 32) {
        // stage A tile 256x32 bf16: 4 rounds x 16B/thread, coalesced
#pragma unroll
        for (int e = 0; e < 4; e++) {
            int chunk = t + e * 256;           // 0..1023
            int r = chunk >> 2, c = chunk & 3;
            int k = k0 + c * 8;
            const ushort_t* src;
            if (CONCAT && k >= half) src = A2 + (size_t)(rowBase + r) * lda + (k - half);
            else                     src = A  + (size_t)(rowBase + r) * lda + k;
            *(ushort8*)&As[r * 40 + c * 8] = *(const ushort8*)src;
        }
        // stage B tile 64x32 bf16 (rows of Wt): 1 round
        {
            int r = t >> 2, c = t & 3;
            *(ushort8*)&Bs[r * 40 + c * 8] =
                *(const ushort8*)(Wt + (size_t)(nBase + r) * KP + k0 + c * 8);
        }
        __syncthreads();

        bf16x8 af[4], bfr[4];
#pragma unroll
        for (int mb = 0; mb < 4; mb++)
            af[mb] = *(const bf16x8*)&As[(wv * 64 + mb * 16 + lrow) * 40 + lgrp * 8];
#pragma unroll
        for (int nb = 0; nb < 4; nb++)
            bfr[nb] = *(const bf16x8*)&Bs[(nb * 16 + lrow) * 40 + lgrp * 8];
#pragma unroll
        for (int mb = 0; mb < 4; mb++)
#pragma unroll
            for (int nb = 0; nb < 4; nb++)
                acc[mb][nb] = __builtin_amdgcn_mfma_f32_16x16x32_bf16(
                    af[mb], bfr[nb], acc[mb][nb], 0, 0, 0);
        __syncthreads();
    }

    // epilogue: D layout col=lane&15, row=(lane>>4)*4+r  (m89/m91)
#pragma unroll
    for (int mb = 0; mb < 4; mb++) {
        int row0 = rowBase + wv * 64 + mb * 16 + lgrp * 4;
#pragma unroll
        for (int nb = 0; nb < 4; nb++) {
            int col = nBase + nb * 16 + lrow;
            float bv = 0.f;
            if (BIAS) bv = (col < Hh) ? bias[col] : 0.f;
#pragma unroll
            for (int r = 0; r < 4; r++) {
                float v = acc[mb][nb][r] + bv;
                if (RELU) v = v > 0.f ? v : 0.f;
                C[(size_t)(row0 + r) * Hp + col] = f2bf(v);
            }
        }
    }
}

// ---------------------------------------------------------------------------
// Gather over neighbors. One wave per node, 4 nodes / 256-thread block.
// LABEL: label[node,h] = sum_k relu(Au2[ia,h] + (fb@Wu2b)[h] + b_u2[h]) (bf16 out)
// FINAL: dot = nmask * sum_h (sum_k Ana[ia,h]*(fb@Wnb)[h]) * Asa[node,h]*Wout[h]
//        block-reduced, one atomicAdd per block (all 4 nodes share batch b).
// ---------------------------------------------------------------------------
template<bool FINAL>
__global__ __launch_bounds__(256)
void gather_k(const ushort_t* __restrict__ Arow,   // bf16 [R][320]
              const ushort_t* __restrict__ Asa,    // FINAL only, bf16 [R][320]
              const float* __restrict__ bond,      // [B*M, 6] fp32
              const float* __restrict__ Wb,        // 6 x 300 fp32
              const float* __restrict__ bias,      // b_u2 (LABEL)
              const int*   __restrict__ ag,
              const int*   __restrict__ bg,
              const int*   __restrict__ nnb,
              const float* __restrict__ nmask,     // FINAL
              const float* __restrict__ Wout,      // FINAL
              void* __restrict__ outp)             // bf16 label [R][320] or f32 out[B]
{
    __shared__ float sWb[6 * Hh];
    __shared__ float sV[Hh];
    __shared__ float sdot[4];
    for (int i = threadIdx.x; i < 6 * Hh; i += 256) sWb[i] = Wb[i];
    if (FINAL) { for (int i = threadIdx.x; i < Hh; i += 256) sV[i] = Wout[i]; }
    else       { for (int i = threadIdx.x; i < Hh; i += 256) sV[i] = bias[i]; }
    __syncthreads();

    const int wave = threadIdx.x >> 6;
    const int lane = threadIdx.x & 63;
    const int node = blockIdx.x * 4 + wave;
    const int b    = node >> 11;               // N = 2048
    const int nn   = nnb[node];
    const int base = node * NBn;

    float acc[5] = {0.f, 0.f, 0.f, 0.f, 0.f};

    for (int k = 0; k < nn; k++) {             // nn wave-uniform
        int ia = ag[base + k];
        int ib = bg[base + k];
        const ushort_t* pa = Arow + ((size_t)(b << 11) + ia) * Hp;
        const float*    pf = bond + ((size_t)(b << 12) + ib) * 6;
        float f0 = pf[0], f1 = pf[1], f2 = pf[2], f3 = pf[3], f4 = pf[4], f5 = pf[5];
#pragma unroll
        for (int j = 0; j < 5; j++) {
            int h = lane + j * 64;
            if (j < 4 || h < Hh) {
                float w = f0 * sWb[h]          + f1 * sWb[Hh + h]
                        + f2 * sWb[2 * Hh + h] + f3 * sWb[3 * Hh + h]
                        + f4 * sWb[4 * Hh + h] + f5 * sWb[5 * Hh + h];
                float av = bf2f(pa[h]);
                if (FINAL) {
                    acc[j] += av * w;
                } else {
                    float v = av + w + sV[h];
                    acc[j] += v > 0.f ? v : 0.f;
                }
            }
        }
    }

    if (FINAL) {
        const ushort_t* psa = Asa + (size_t)node * Hp;
        float dot = 0.f;
#pragma unroll
        for (int j = 0; j < 5; j++) {
            int h = lane + j * 64;
            if (j < 4 || h < Hh) dot += acc[j] * bf2f(psa[h]) * sV[h];
        }
        dot *= nmask[node];
#pragma unroll
        for (int off = 32; off > 0; off >>= 1) dot += __shfl_down(dot, off, 64);
        if (lane == 0) sdot[wave] = dot;
        __syncthreads();
        if (threadIdx.x == 0) {
            // all 4 nodes in this block share batch b (2048 % 4 == 0)
            atomicAdd(&((float*)outp)[b], sdot[0] + sdot[1] + sdot[2] + sdot[3]);
        }
    } else {
        ushort_t* pl = (ushort_t*)outp + (size_t)node * Hp;
#pragma unroll
        for (int j = 0; j < 5; j++) {
            int h = lane + j * 64;
            if (h < Hh)      pl[h] = f2bf(acc[j]);
            else if (h < Hp) pl[h] = 0;          // keep pads zero every call
        }
    }
}

// ---------------------------------------------------------------------------
__global__ void zero_k(ushort_t* __restrict__ p, int n)
{
    int i = blockIdx.x * 256 + threadIdx.x;
    if (i < n) p[i] = 0;
}

__global__ void cvt_atom_k(const float* __restrict__ src, ushort_t* __restrict__ dst)
{
    int idx = blockIdx.x * 256 + threadIdx.x;    // over R*96
    if (idx >= Rn * 96) return;
    int r = idx / 96, c = idx - r * 96;
    dst[idx] = (c < 82) ? f2bf(src[r * 82 + c]) : (ushort_t)0;
}

// src fp32 [Ksrc][300] -> dst bf16 [320][stride] transposed at column kbase
__global__ void cvt_w_k(const float* __restrict__ src, ushort_t* __restrict__ dst,
                        int Ksrc, int kbase, int stride)
{
    int idx = blockIdx.x * 256 + threadIdx.x;
    if (idx >= Ksrc * Hh) return;
    int k = idx / Hh, n = idx - k * Hh;
    dst[(size_t)n * stride + kbase + k] = f2bf(src[idx]);
}

__global__ void init_out_k(float* __restrict__ out, const float* __restrict__ b_out)
{
    if (threadIdx.x < Bn) out[threadIdx.x] = b_out[0];
}

// ---------------------------------------------------------------------------
extern "C" void kernel_launch(void* const* d_in, const int* in_sizes, int n_in,
                              void* d_out, int out_size, void* d_ws, size_t ws_size,
                              hipStream_t stream)
{
    const float* input_atom = (const float*)d_in[0];
    const float* input_bond = (const float*)d_in[1];
    const float* node_mask  = (const float*)d_in[2];
    const int*   atom_graph = (const int*)d_in[3];
    const int*   bond_graph = (const int*)d_in[4];
    const int*   num_nbs    = (const int*)d_in[5];
    const float* W_af       = (const float*)d_in[6];
    const float* W_na       = (const float*)d_in[7];
    const float* W_nb       = (const float*)d_in[8];
    const float* W_sa       = (const float*)d_in[9];
    const float* W_u2       = (const float*)d_in[10];
    const float* b_u2       = (const float*)d_in[11];
    const float* W_u1       = (const float*)d_in[12];
    const float* b_u1       = (const float*)d_in[13];
    const float* W_out      = (const float*)d_in[14];
    const float* b_out      = (const float*)d_in[15];
    float* out = (float*)d_out;

    const float* W_u2b = W_u2 + (size_t)Hh * Hh;   // rows 300..305 (bond part)

    const size_t S2 = (size_t)Rn * Hp;             // 10,485,760 bf16 per buffer
    ushort_t* bufA0 = (ushort_t*)d_ws;
    ushort_t* bufA1 = bufA0 + S2;
    ushort_t* bufP  = bufA1 + S2;                  // A_u2 / A_na projections
    ushort_t* bufL  = bufP  + S2;                  // nei_label
    ushort_t* bufS  = bufL  + S2;                  // A_sa
    ushort_t* iaB   = bufS  + S2;                  // input_atom bf16 [R][96]
    ushort_t* wAf   = iaB + (size_t)Rn * 96;       // [320][96]
    ushort_t* wU2   = wAf + 320 * 96;              // [320][320]
    ushort_t* wNa   = wU2 + 320 * 320;
    ushort_t* wSa   = wNa + 320 * 320;
    ushort_t* wU1   = wSa + 320 * 320;             // [320][640]

    // zero weight region (covers all pads), then convert weights/inputs
    const int wElems = 320 * 96 + 3 * 320 * 320 + 320 * 640;   // 542,720
    zero_k<<<(wElems + 255) / 256, 256, 0, stream>>>(wAf, wElems);
    cvt_atom_k<<<(Rn * 96 + 255) / 256, 256, 0, stream>>>(input_atom, iaB);
    cvt_w_k<<<( 82 * 300 + 255) / 256, 256, 0, stream>>>(W_af, wAf,  82,   0,  96);
    cvt_w_k<<<(300 * 300 + 255) / 256, 256, 0, stream>>>(W_u2, wU2, 300,   0, 320);
    cvt_w_k<<<(300 * 300 + 255) / 256, 256, 0, stream>>>(W_na, wNa, 300,   0, 320);
    cvt_w_k<<<(300 * 300 + 255) / 256, 256, 0, stream>>>(W_sa, wSa, 300,   0, 320);
    cvt_w_k<<<(300 * 300 + 255) / 256, 256, 0, stream>>>(W_u1, wU1, 300,   0, 640);
    cvt_w_k<<<(300 * 300 + 255) / 256, 256, 0, stream>>>(W_u1 + 300 * 300, wU1, 300, 320, 640);
    init_out_k<<<dim3(1), dim3(64), 0, stream>>>(out, b_out);

    dim3 gg(5, Rn / 256);                          // 5 col tiles x 128 row tiles
    const int gb = Rn / 4;                         // gather blocks

    // atom_feat0 = relu(input_atom @ W_af)
    mfma_gemm_k<true, false, false><<<gg, 256, 0, stream>>>(
        iaB, nullptr, 96, 96, wAf, nullptr, bufA0);

    ushort_t* cur = bufA0;
    ushort_t* oth = bufA1;
    for (int d = 0; d < 2; d++) {
        mfma_gemm_k<false, false, false><<<gg, 256, 0, stream>>>(
            cur, nullptr, Hp, Hp, wU2, nullptr, bufP);
        gather_k<false><<<gb, 256, 0, stream>>>(
            bufP, nullptr, input_bond, W_u2b, b_u2,
            atom_graph, bond_graph, num_nbs, nullptr, nullptr, bufL);
        mfma_gemm_k<true, true, true><<<gg, 256, 0, stream>>>(
            cur, bufL, Hp, 2 * Hp, wU1, b_u1, oth);
        ushort_t* tmp = cur; cur = oth; oth = tmp;
    }

    // depth 2: only the kernel output is live
    mfma_gemm_k<false, false, false><<<gg, 256, 0, stream>>>(
        cur, nullptr, Hp, Hp, wNa, nullptr, bufP);
    mfma_gemm_k<false, false, false><<<gg, 256, 0, stream>>>(
        cur, nullptr, Hp, Hp, wSa, nullptr, bufS);
    gather_k<true><<<gb, 256, 0, stream>>>(
        bufP, bufS, input_bond, W_nb, nullptr,
        atom_graph, bond_graph, num_nbs, node_mask, W_out, out);
}

// Round 3
// 491.934 us; speedup vs baseline: 4.8419x; 1.1233x over previous
//
#include <hip/hip_runtime.h>
#include <math.h>

// WLN regressor, bf16-MFMA + pipelined-gather version.
//  - gather commutes with row-wise matmul: gather(X)@W == gather(X@W)
//  - kernel (W_na/W_sa path) only live at last depth; U1 update dead after depth 1
//  - all GEMMs on matrix cores (16x16x32 bf16), activations bf16 [R][320]
//  - gathers: shfl-broadcast index prefetch + depth-2 load pipeline

typedef unsigned short ushort_t;
typedef __attribute__((ext_vector_type(8))) short bf16x8;
typedef __attribute__((ext_vector_type(8))) unsigned short ushort8;
typedef __attribute__((ext_vector_type(4))) float f32x4;

static constexpr int Hh  = 300;
static constexpr int Hp  = 320;      // padded hidden (col dim & activation stride)
static constexpr int Bn  = 16;
static constexpr int Nn  = 2048;
static constexpr int Rn  = Bn * Nn;  // 32768 rows
static constexpr int NBn = 10;

// weight-region offsets (in ushorts, relative to wAf)
static constexpr size_t OFF_U2 = 320 * 96;
static constexpr size_t OFF_NA = OFF_U2 + 320 * 320;
static constexpr size_t OFF_SA = OFF_NA + 320 * 320;
static constexpr size_t OFF_U1 = OFF_SA + 320 * 320;
static constexpr int    W_ELEMS = (int)(OFF_U1 + 320 * 640);

__device__ __forceinline__ ushort_t f2bf(float x) {
    union { float f; unsigned u; } c; c.f = x;
    unsigned r = c.u + 0x7FFFu + ((c.u >> 16) & 1u);   // RNE
    return (ushort_t)(r >> 16);
}
__device__ __forceinline__ float bf2f(ushort_t h) {
    union { float f; unsigned u; } c; c.u = ((unsigned)h) << 16;
    return c.f;
}

// ---------------------------------------------------------------------------
// MFMA GEMM: C[r,n] = act( sum_k Asel[r,k]*Wt[n,k] (+bias[n]) ), C bf16 [R][320]
// BM=256, BN=64, BK=32; 256 threads = 4 waves, each wave 64x64.
// LDS rows padded to 40 bf16 (80B) -> worst 2-way bank conflict (free).
// ---------------------------------------------------------------------------
template<bool RELU, bool BIAS, bool CONCAT>
__global__ __launch_bounds__(256)
void mfma_gemm_k(const ushort_t* __restrict__ A, const ushort_t* __restrict__ A2,
                 int lda, int KP,
                 const ushort_t* __restrict__ Wt,
                 const float* __restrict__ bias,
                 ushort_t* __restrict__ C)
{
    __shared__ __attribute__((aligned(16))) ushort_t As[256 * 40];
    __shared__ __attribute__((aligned(16))) ushort_t Bs[64 * 40];

    const int t   = threadIdx.x;
    const int wv  = t >> 6;
    const int ln  = t & 63;
    const int lrow = ln & 15;
    const int lgrp = ln >> 4;
    const int rowBase = blockIdx.y * 256;
    const int nBase   = blockIdx.x * 64;

    f32x4 acc[4][4];
#pragma unroll
    for (int i = 0; i < 4; i++)
#pragma unroll
        for (int j = 0; j < 4; j++) acc[i][j] = (f32x4){0.f, 0.f, 0.f, 0.f};

    const int half = KP >> 1;

    for (int k0 = 0; k0 < KP; k0 += 32) {
#pragma unroll
        for (int e = 0; e < 4; e++) {
            int chunk = t + e * 256;
            int r = chunk >> 2, c = chunk & 3;
            int k = k0 + c * 8;
            const ushort_t* src;
            if (CONCAT && k >= half) src = A2 + (size_t)(rowBase + r) * lda + (k - half);
            else                     src = A  + (size_t)(rowBase + r) * lda + k;
            *(ushort8*)&As[r * 40 + c * 8] = *(const ushort8*)src;
        }
        {
            int r = t >> 2, c = t & 3;
            *(ushort8*)&Bs[r * 40 + c * 8] =
                *(const ushort8*)(Wt + (size_t)(nBase + r) * KP + k0 + c * 8);
        }
        __syncthreads();

        bf16x8 af[4], bfr[4];
#pragma unroll
        for (int mb = 0; mb < 4; mb++)
            af[mb] = *(const bf16x8*)&As[(wv * 64 + mb * 16 + lrow) * 40 + lgrp * 8];
#pragma unroll
        for (int nb = 0; nb < 4; nb++)
            bfr[nb] = *(const bf16x8*)&Bs[(nb * 16 + lrow) * 40 + lgrp * 8];
#pragma unroll
        for (int mb = 0; mb < 4; mb++)
#pragma unroll
            for (int nb = 0; nb < 4; nb++)
                acc[mb][nb] = __builtin_amdgcn_mfma_f32_16x16x32_bf16(
                    af[mb], bfr[nb], acc[mb][nb], 0, 0, 0);
        __syncthreads();
    }

#pragma unroll
    for (int mb = 0; mb < 4; mb++) {
        int row0 = rowBase + wv * 64 + mb * 16 + lgrp * 4;
#pragma unroll
        for (int nb = 0; nb < 4; nb++) {
            int col = nBase + nb * 16 + lrow;
            float bv = 0.f;
            if (BIAS) bv = (col < Hh) ? bias[col] : 0.f;
#pragma unroll
            for (int r = 0; r < 4; r++) {
                float v = acc[mb][nb][r] + bv;
                if (RELU) v = v > 0.f ? v : 0.f;
                C[(size_t)(row0 + r) * Hp + col] = f2bf(v);
            }
        }
    }
}

// ---------------------------------------------------------------------------
// Gather. 2048 blocks x 4 waves; each wave grid-strides over 4 nodes.
// Index prefetch: lanes 0..9 hold ag/bg, __shfl broadcasts per k.
// Depth-2 pipeline on (bond row, atom row) loads, named slots A/B.
// sWb/sV zero-padded to 320 -> no bounds guards anywhere.
// ---------------------------------------------------------------------------
template<bool FINAL>
__global__ __launch_bounds__(256)
void gather_k(const ushort_t* __restrict__ Arow,   // bf16 [R][320]
              const ushort_t* __restrict__ Asa,    // FINAL only
              const float* __restrict__ bond,      // [B*M, 6] fp32
              const float* __restrict__ Wb,        // 6 x 300 fp32
              const float* __restrict__ bias,      // b_u2 (LABEL)
              const int*   __restrict__ ag,
              const int*   __restrict__ bg,
              const int*   __restrict__ nnb,
              const float* __restrict__ nmask,     // FINAL
              const float* __restrict__ Wout,      // FINAL
              void* __restrict__ outp)             // bf16 label [R][320] or f32 out[B]
{
    __shared__ float sWb[6 * Hp];
    __shared__ float sV[Hp];
    __shared__ float sdot[4];
    for (int i = threadIdx.x; i < 6 * Hp; i += 256) {
        int tt = i / Hp, h = i - tt * Hp;
        sWb[i] = (h < Hh) ? Wb[tt * Hh + h] : 0.f;
    }
    for (int i = threadIdx.x; i < Hp; i += 256) {
        float v = 0.f;
        if (i < Hh) v = FINAL ? Wout[i] : bias[i];
        sV[i] = v;
    }
    __syncthreads();

    const int wave = threadIdx.x >> 6;
    const int lane = threadIdx.x & 63;

    int node = blockIdx.x * 4 + wave;

    for (int it = 0; it < 4; it++, node += 2048 * 4) {
        const int b    = node >> 11;               // N = 2048
        const int nn   = nnb[node];
        const int base = node * NBn;
        const size_t arow0 = (size_t)(b << 11) * Hp;
        const size_t brow0 = (size_t)(b << 12) * 6;

        const int iav = ag[base + (lane < 10 ? lane : 9)];
        const int ibv = bg[base + (lane < 10 ? lane : 9)];

        float acc[5] = {0.f, 0.f, 0.f, 0.f, 0.f};
        float cA[6], cB[6];
        ushort_t qA[5], qB[5];

        auto issue = [&](int kk, float (&c)[6], ushort_t (&q)[5]) {
            int iak = __shfl(iav, kk);
            int ibk = __shfl(ibv, kk);
            const ushort_t* pa = Arow + arow0 + (size_t)iak * Hp + lane;
            const float*    pf = bond + brow0 + (size_t)ibk * 6;
#pragma unroll
            for (int j = 0; j < 5; j++) q[j] = pa[j * 64];
#pragma unroll
            for (int t2 = 0; t2 < 6; t2++) c[t2] = pf[t2];
        };
        auto consume = [&](const float (&c)[6], const ushort_t (&q)[5]) {
#pragma unroll
            for (int j = 0; j < 5; j++) {
                int h = lane + j * 64;
                float w = c[0] * sWb[h]          + c[1] * sWb[Hp + h]
                        + c[2] * sWb[2 * Hp + h] + c[3] * sWb[3 * Hp + h]
                        + c[4] * sWb[4 * Hp + h] + c[5] * sWb[5 * Hp + h];
                float av = bf2f(q[j]);
                if (FINAL) {
                    acc[j] += av * w;
                } else {
                    float v = av + w + sV[h];
                    acc[j] += v > 0.f ? v : 0.f;
                }
            }
        };

        if (nn > 0) {
            issue(0, cA, qA);
            if (nn > 1) issue(1, cB, qB);
            for (int k = 0; k < nn; k += 2) {
                consume(cA, qA);
                if (k + 2 < nn) issue(k + 2, cA, qA);
                if (k + 1 < nn) {
                    consume(cB, qB);
                    if (k + 3 < nn) issue(k + 3, cB, qB);
                }
            }
        }

        if (FINAL) {
            const ushort_t* psa = Asa + (size_t)node * Hp + lane;
            float dot = 0.f;
#pragma unroll
            for (int j = 0; j < 5; j++) {
                int h = lane + j * 64;
                dot += acc[j] * bf2f(psa[j * 64]) * sV[h];
            }
            dot *= nmask[node];
#pragma unroll
            for (int off = 32; off > 0; off >>= 1) dot += __shfl_down(dot, off, 64);
            if (lane == 0) sdot[wave] = dot;
            __syncthreads();
            if (threadIdx.x == 0)
                atomicAdd(&((float*)outp)[b], sdot[0] + sdot[1] + sdot[2] + sdot[3]);
            __syncthreads();                       // protect sdot reuse next iter
        } else {
            ushort_t* pl = (ushort_t*)outp + (size_t)node * Hp + lane;
#pragma unroll
            for (int j = 0; j < 5; j++) pl[j * 64] = f2bf(acc[j]);
        }
    }
}

// ---------------------------------------------------------------------------
__global__ void zero_k(ushort_t* __restrict__ p, int n)
{
    int i = blockIdx.x * 256 + threadIdx.x;
    if (i < n) p[i] = 0;
}

__global__ void cvt_atom_k(const float* __restrict__ src, ushort_t* __restrict__ dst)
{
    int idx = blockIdx.x * 256 + threadIdx.x;    // over R*96
    if (idx >= Rn * 96) return;
    int r = idx / 96, c = idx - r * 96;
    dst[idx] = (c < 82) ? f2bf(src[r * 82 + c]) : (ushort_t)0;
}

// all weight conversions in one launch; grid.y selects segment
__global__ void cvt_weights_k(const float* __restrict__ W_af,
                              const float* __restrict__ W_u2,
                              const float* __restrict__ W_na,
                              const float* __restrict__ W_sa,
                              const float* __restrict__ W_u1,
                              ushort_t* __restrict__ dst0)
{
    const float* src; int Ksrc, kbase, stride; size_t doff;
    switch (blockIdx.y) {
    case 0:  src = W_af;             Ksrc =  82; kbase = 0;   stride =  96; doff = 0;      break;
    case 1:  src = W_u2;             Ksrc = 300; kbase = 0;   stride = 320; doff = OFF_U2; break;
    case 2:  src = W_na;             Ksrc = 300; kbase = 0;   stride = 320; doff = OFF_NA; break;
    case 3:  src = W_sa;             Ksrc = 300; kbase = 0;   stride = 320; doff = OFF_SA; break;
    case 4:  src = W_u1;             Ksrc = 300; kbase = 0;   stride = 640; doff = OFF_U1; break;
    default: src = W_u1 + 300 * 300; Ksrc = 300; kbase = 320; stride = 640; doff = OFF_U1; break;
    }
    int idx = blockIdx.x * 256 + threadIdx.x;
    if (idx >= Ksrc * Hh) return;
    int k = idx / Hh, n = idx - k * Hh;
    dst0[doff + (size_t)n * stride + kbase + k] = f2bf(src[idx]);
}

__global__ void init_out_k(float* __restrict__ out, const float* __restrict__ b_out)
{
    if (threadIdx.x < Bn) out[threadIdx.x] = b_out[0];
}

// ---------------------------------------------------------------------------
extern "C" void kernel_launch(void* const* d_in, const int* in_sizes, int n_in,
                              void* d_out, int out_size, void* d_ws, size_t ws_size,
                              hipStream_t stream)
{
    const float* input_atom = (const float*)d_in[0];
    const float* input_bond = (const float*)d_in[1];
    const float* node_mask  = (const float*)d_in[2];
    const int*   atom_graph = (const int*)d_in[3];
    const int*   bond_graph = (const int*)d_in[4];
    const int*   num_nbs    = (const int*)d_in[5];
    const float* W_af       = (const float*)d_in[6];
    const float* W_na       = (const float*)d_in[7];
    const float* W_nb       = (const float*)d_in[8];
    const float* W_sa       = (const float*)d_in[9];
    const float* W_u2       = (const float*)d_in[10];
    const float* b_u2       = (const float*)d_in[11];
    const float* W_u1       = (const float*)d_in[12];
    const float* b_u1       = (const float*)d_in[13];
    const float* W_out      = (const float*)d_in[14];
    const float* b_out      = (const float*)d_in[15];
    float* out = (float*)d_out;

    const float* W_u2b = W_u2 + (size_t)Hh * Hh;   // rows 300..305 (bond part)

    const size_t S2 = (size_t)Rn * Hp;             // bf16 elems per activation buffer
    ushort_t* bufA0 = (ushort_t*)d_ws;
    ushort_t* bufA1 = bufA0 + S2;
    ushort_t* bufP  = bufA1 + S2;                  // A_u2 / A_na projections
    ushort_t* bufL  = bufP  + S2;                  // nei_label
    ushort_t* bufS  = bufL  + S2;                  // A_sa
    ushort_t* iaB   = bufS  + S2;                  // input_atom bf16 [R][96]
    ushort_t* wAf   = iaB + (size_t)Rn * 96;       // weight region base

    zero_k<<<(W_ELEMS + 255) / 256, 256, 0, stream>>>(wAf, W_ELEMS);
    cvt_atom_k<<<(Rn * 96 + 255) / 256, 256, 0, stream>>>(input_atom, iaB);
    cvt_weights_k<<<dim3(352, 6), 256, 0, stream>>>(W_af, W_u2, W_na, W_sa, W_u1, wAf);
    init_out_k<<<dim3(1), dim3(64), 0, stream>>>(out, b_out);

    dim3 gg(5, Rn / 256);
    const int gb = 2048;                           // gather blocks (grid-stride x4)

    mfma_gemm_k<true, false, false><<<gg, 256, 0, stream>>>(
        iaB, nullptr, 96, 96, wAf, nullptr, bufA0);

    ushort_t* cur = bufA0;
    ushort_t* oth = bufA1;
    for (int d = 0; d < 2; d++) {
        mfma_gemm_k<false, false, false><<<gg, 256, 0, stream>>>(
            cur, nullptr, Hp, Hp, wAf + OFF_U2, nullptr, bufP);
        gather_k<false><<<gb, 256, 0, stream>>>(
            bufP, nullptr, input_bond, W_u2b, b_u2,
            atom_graph, bond_graph, num_nbs, nullptr, nullptr, bufL);
        mfma_gemm_k<true, true, true><<<gg, 256, 0, stream>>>(
            cur, bufL, Hp, 2 * Hp, wAf + OFF_U1, b_u1, oth);
        ushort_t* tmp = cur; cur = oth; oth = tmp;
    }

    // depth 2: only the kernel output is live
    mfma_gemm_k<false, false, false><<<gg, 256, 0, stream>>>(
        cur, nullptr, Hp, Hp, wAf + OFF_NA, nullptr, bufP);
    mfma_gemm_k<false, false, false><<<gg, 256, 0, stream>>>(
        cur, nullptr, Hp, Hp, wAf + OFF_SA, nullptr, bufS);
    gather_k<true><<<gb, 256, 0, stream>>>(
        bufP, bufS, input_bond, W_nb, nullptr,
        atom_graph, bond_graph, num_nbs, node_mask, W_out, out);
}